// Round 10
// baseline (327.992 us; speedup 1.0000x reference)
//
#include <hip/hip_runtime.h>
#include <hip/hip_bf16.h>
#include <stdint.h>

#define NN 100000
#define NE 1600000
#define DF 128
#define DH 256
#define NC 40
#define BSHIFT 8
#define NBKT 391          // ceil(NN/256) buckets, bucket = dst>>8
#define EPB 8192          // edges per k_bin block
#define NBIN_BLOCKS ((NE + EPB - 1) / EPB)   // 196
#define BKT_SLACK 2048    // >= 7*256 max padding per bucket, 256-aligned

typedef __attribute__((ext_vector_type(8))) short short8;
typedef __attribute__((ext_vector_type(4))) float f32x4;

typedef const __attribute__((address_space(1))) unsigned int* gas1;
typedef __attribute__((address_space(3))) unsigned int* las3;

__device__ __forceinline__ void gload16(const void* g, void* l) {
  __builtin_amdgcn_global_load_lds((gas1)g, (las3)l, 16, 0, 0);
}

__device__ __forceinline__ unsigned short f2bf(float f) {
  union { float f; unsigned u; } v; v.f = f;
  unsigned r = v.u + 0x7FFFu + ((v.u >> 16) & 1u);
  return (unsigned short)(r >> 16);
}
__device__ __forceinline__ float bflo(unsigned u) {
  union { unsigned u; float f; } v; v.u = u << 16; return v.f;
}
__device__ __forceinline__ float bfhi(unsigned u) {
  union { unsigned u; float f; } v; v.u = u & 0xFFFF0000u; return v.f;
}

// ---------------- x -> bf16 pre-convert (+ zero row NN) ----------------
__global__ void k_xbf16(const float* __restrict__ x, unsigned* __restrict__ xb) {
  int i = blockIdx.x * blockDim.x + threadIdx.x;
  if (i < (NN + 1) * 64) {
    unsigned pk = 0u;
    if (i < NN * 64) {
      float2 v = ((const float2*)x)[i];
      pk = ((unsigned)f2bf(v.y) << 16) | f2bf(v.x);
    }
    xb[i] = pk;
  }
}

// ---------------- CSR build: bucket counting sort (padded output) ----------------
__global__ __launch_bounds__(256) void k_bhist(const int* __restrict__ dst, int* __restrict__ bcnt) {
  __shared__ int h[NBKT];
  int tid = threadIdx.x;
  for (int b = tid; b < NBKT; b += 256) h[b] = 0;
  __syncthreads();
  int base = blockIdx.x * EPB;
  int n = NE - base; if (n > EPB) n = EPB;
  for (int i = tid; i < n; i += 256) atomicAdd(&h[dst[base + i] >> BSHIFT], 1);
  __syncthreads();
  for (int b = tid; b < NBKT; b += 256) if (h[b]) atomicAdd(&bcnt[b], h[b]);
}

// scan buckets -> bases; init cursors; also zero Pb row NN
__global__ __launch_bounds__(512) void k_bscan(const int* __restrict__ bcnt,
                                               int* __restrict__ boff, int* __restrict__ bcur,
                                               unsigned short* __restrict__ Pb) {
  __shared__ int s[512];
  int tid = threadIdx.x;
  int v = (tid < NBKT) ? bcnt[tid] : 0;
  s[tid] = v;
  __syncthreads();
  for (int off = 1; off < 512; off <<= 1) {
    int a = (tid >= off) ? s[tid - off] : 0;
    __syncthreads();
    s[tid] += a;
    __syncthreads();
  }
  int excl = s[tid] - v;
  if (tid < NBKT) { boff[tid] = excl; bcur[tid] = excl; }
  if (tid == NBKT) boff[NBKT] = excl;   // == total (v=0 beyond NBKT)
  if (tid >= 448 && tid < 480) ((unsigned*)(Pb + (size_t)NN * 64))[tid - 448] = 0u;
}

__global__ __launch_bounds__(256) void k_bin(const int* __restrict__ src, const int* __restrict__ dst,
                                             int* __restrict__ bcur, unsigned* __restrict__ pairs) {
  __shared__ int hcnt[NBKT];
  __shared__ int hbase[NBKT];
  int tid = threadIdx.x;
  for (int b = tid; b < NBKT; b += 256) hcnt[b] = 0;
  __syncthreads();
  int base = blockIdx.x * EPB;
  int n = NE - base; if (n > EPB) n = EPB;
  for (int i = tid; i < n; i += 256) atomicAdd(&hcnt[dst[base + i] >> BSHIFT], 1);
  __syncthreads();
  for (int b = tid; b < NBKT; b += 256) hbase[b] = hcnt[b] ? atomicAdd(&bcur[b], hcnt[b]) : 0;
  __syncthreads();
  for (int b = tid; b < NBKT; b += 256) hcnt[b] = 0;
  __syncthreads();
  for (int i = tid; i < n; i += 256) {
    int s = src[base + i], d = dst[base + i];
    int b = d >> BSHIFT;
    int slot = atomicAdd(&hcnt[b], 1);
    pairs[hbase[b] + slot] = (unsigned)s | ((unsigned)(d & 255) << 17);
  }
}

// per-bucket padded CSR: deg[] + row_ptr8[] + csr8[] (lists padded to x8 with src=NN)
__global__ __launch_bounds__(256) void k_csr(const unsigned* __restrict__ pairs,
                                             const int* __restrict__ boff,
                                             int* __restrict__ deg, int* __restrict__ row_ptr8,
                                             int* __restrict__ csr8) {
  __shared__ int ncnt[256];
  __shared__ int noff[256];
  int tid = threadIdx.x;
  int b = blockIdx.x;
  int base = boff[b], end = boff[b + 1];
  int base8 = base + BKT_SLACK * b;
  ncnt[tid] = 0;
  __syncthreads();
  for (int e = base + tid; e < end; e += 256) atomicAdd(&ncnt[pairs[e] >> 17], 1);
  __syncthreads();
  int cnt = ncnt[tid];
  int pcnt = (cnt + 7) & ~7;
  noff[tid] = pcnt;
  __syncthreads();
  for (int off = 1; off < 256; off <<= 1) {
    int a = (tid >= off) ? noff[tid - off] : 0;
    __syncthreads();
    noff[tid] += a;
    __syncthreads();
  }
  int pexcl = noff[tid] - pcnt;
  __syncthreads();
  noff[tid] = pexcl;
  ncnt[tid] = 0;
  __syncthreads();
  int gnode = (b << BSHIFT) + tid;
  if (gnode < NN) { deg[gnode] = cnt; row_ptr8[gnode] = base8 + pexcl; }
  // scatter real edges
  for (int e = base + tid; e < end; e += 256) {
    unsigned p = pairs[e];
    int ld = p >> 17;
    int slot = atomicAdd(&ncnt[ld], 1);
    csr8[base8 + noff[ld] + slot] = (int)(p & 0x1FFFFu);
  }
  // pad slots -> zero row
  for (int k = cnt; k < pcnt; ++k) csr8[base8 + pexcl + k] = NN;
}

// ---------------- weight pack (f32 -> bf16, concat) ----------------
__global__ void k_packw(const float* __restrict__ w1l, const float* __restrict__ w1r,
                        const float* __restrict__ w2l, const float* __restrict__ w2r,
                        unsigned short* __restrict__ Wc, unsigned short* __restrict__ W2c) {
  int i = blockIdx.x * blockDim.x + threadIdx.x;
  if (i < 256 * 256) {
    int o = i >> 8, k = i & 255;
    float v = (k < 128) ? w1l[o * 128 + k] : w1r[o * 128 + (k - 128)];
    Wc[i] = f2bf(v);
  }
  int j = i - 256 * 256;
  if (j >= 0 && j < 80 * 256) {
    int o = j >> 8, k = j & 255;
    float v = (o < 40) ? w2l[o * 256 + k] : w2r[(o - 40) * 256 + k];
    W2c[j] = f2bf(v);
  }
}

// ---------------- layer-1 aggregation: A1 = mean-agg(xb), edge-paired dwordx2 gathers ----------------
// lanes 0-31 process even edge slots, 32-63 odd slots; 8B/lane; no tails (padded CSR)
__global__ void k_agg1(const unsigned* __restrict__ xb, const int* __restrict__ row_ptr8,
                       const int* __restrict__ deg, const int* __restrict__ csr8,
                       unsigned* __restrict__ A1) {
  int w = threadIdx.x >> 6, lane = threadIdx.x & 63;
  int node = blockIdx.x * 4 + w;
  if (node >= NN) return;
  int dg = deg[node];
  int rs = row_ptr8[node];
  int pdeg = (dg + 7) & ~7;
  int half = lane >> 5, li = lane & 31;
  float a0 = 0.f, a1 = 0.f, a2 = 0.f, a3 = 0.f;
  const unsigned* xp = xb + li * 2;
  for (int e = rs; e < rs + pdeg; e += 8) {
#pragma unroll
    for (int j = 0; j < 4; ++j) {
      int idx = csr8[e + 2 * j + half];
      uint2 v = *(const uint2*)(xp + (size_t)idx * 64);
      a0 += bflo(v.x); a1 += bfhi(v.x);
      a2 += bflo(v.y); a3 += bfhi(v.y);
    }
  }
  a0 += __shfl_xor(a0, 32);
  a1 += __shfl_xor(a1, 32);
  a2 += __shfl_xor(a2, 32);
  a3 += __shfl_xor(a3, 32);
  if (half == 0) {
    float inv = 1.f / (float)(dg > 0 ? dg : 1);
    uint2 pk;
    pk.x = ((unsigned)f2bf(a1 * inv) << 16) | f2bf(a0 * inv);
    pk.y = ((unsigned)f2bf(a3 * inv) << 16) | f2bf(a2 * inv);
    *(uint2*)(A1 + (size_t)node * 64 + li * 2) = pk;
  }
}

// ---------------- fused GEMM1+GEMM2: H tile lives in LDS only ----------------
__global__ __launch_bounds__(256) void k_fused(const unsigned short* __restrict__ A1,
                                               const unsigned short* __restrict__ XB,
                                               const unsigned short* __restrict__ Wc,
                                               const float* __restrict__ b1,
                                               const unsigned short* __restrict__ W2c,
                                               unsigned short* __restrict__ Pb,
                                               float* __restrict__ R) {
  __shared__ __align__(16) unsigned short sA[64 * 64];
  __shared__ __align__(16) unsigned short sB[256 * 64];
  __shared__ __align__(16) unsigned short sH[64 * 256];
  int tid = threadIdx.x;
  int w = tid >> 6, lane = tid & 63;
  int brow = blockIdx.x * 64;
  int wr = (w >> 1) * 32, wc = (w & 1) * 128;
  f32x4 acc[2][8] = {};

  // ---- phase 1 ----
  for (int kt = 0; kt < 4; ++kt) {
    const unsigned short* srcA = (kt < 2) ? A1 : XB;
    int kcol = (kt & 1) * 64;
#pragma unroll
    for (int t = 0; t < 2; ++t) {
      int c = t * 256 + tid;
      int r = c >> 3, cc = c & 7;
      int scc = cc ^ (r & 7);
      int gr = brow + r; if (gr > NN - 1) gr = NN - 1;
      gload16(srcA + (size_t)gr * 128 + kcol + scc * 8, sA + c * 8);
    }
#pragma unroll
    for (int t = 0; t < 8; ++t) {
      int c = t * 256 + tid;
      int r = c >> 3, cc = c & 7;
      int scc = cc ^ (r & 7);
      gload16(Wc + (size_t)r * 256 + kt * 64 + scc * 8, sB + c * 8);
    }
    __syncthreads();
#pragma unroll
    for (int kg = 0; kg < 2; ++kg) {
      short8 af[2], bfr[8];
#pragma unroll
      for (int m = 0; m < 2; ++m) {
        int row = wr + m * 16 + (lane & 15);
        int cch = (kg * 4 + (lane >> 4)) ^ (row & 7);
        af[m] = *(const short8*)(sA + row * 64 + cch * 8);
      }
#pragma unroll
      for (int n = 0; n < 8; ++n) {
        int row = wc + n * 16 + (lane & 15);
        int cch = (kg * 4 + (lane >> 4)) ^ (row & 7);
        bfr[n] = *(const short8*)(sB + row * 64 + cch * 8);
      }
#pragma unroll
      for (int m = 0; m < 2; ++m)
#pragma unroll
        for (int n = 0; n < 8; ++n)
          acc[m][n] = __builtin_amdgcn_mfma_f32_16x16x32_bf16(af[m], bfr[n], acc[m][n], 0, 0, 0);
    }
    __syncthreads();
  }

  // ---- Htile -> sH (bias + relu, swizzled) ----
  {
    int colbase = wc + (lane & 15);
    int rowb = wr + (lane >> 4) * 4;
#pragma unroll
    for (int n = 0; n < 8; ++n) {
      int col = colbase + n * 16;
      float bias = b1[col];
      int g = col >> 3, off = col & 7;
#pragma unroll
      for (int m = 0; m < 2; ++m) {
        int row0 = rowb + m * 16;
#pragma unroll
        for (int q = 0; q < 4; ++q) {
          int row = row0 + q;
          float v = acc[m][n][q] + bias;
          v = v > 0.f ? v : 0.f;
          sH[row * 256 + ((g ^ (row & 7)) << 3) + off] = f2bf(v);
        }
      }
    }
  }
  __syncthreads();

  // ---- phase 2: P^T = W2c @ H^T ----
  f32x4 a2[5] = {};
  int nrow = w * 16 + (lane & 15);
  for (int kt = 0; kt < 4; ++kt) {
#pragma unroll
    for (int t = 0; t < 3; ++t) {
      int c = t * 256 + tid;
      if (c < 640) {
        int r = c >> 3, cc = c & 7;
        int scc = cc ^ (r & 7);
        gload16(W2c + (size_t)r * 256 + kt * 64 + scc * 8, sB + c * 8);
      }
    }
    __syncthreads();
#pragma unroll
    for (int kg = 0; kg < 2; ++kg) {
      int gH = kt * 8 + kg * 4 + (lane >> 4);
      short8 bf1 = *(const short8*)(sH + nrow * 256 + ((gH ^ (nrow & 7)) << 3));
      short8 af[5];
#pragma unroll
      for (int m = 0; m < 5; ++m) {
        int arow = m * 16 + (lane & 15);
        int cch = (kg * 4 + (lane >> 4)) ^ (arow & 7);
        af[m] = *(const short8*)(sB + arow * 64 + cch * 8);
      }
#pragma unroll
      for (int m = 0; m < 5; ++m)
        a2[m] = __builtin_amdgcn_mfma_f32_16x16x32_bf16(af[m], bf1, a2[m], 0, 0, 0);
    }
    __syncthreads();
  }

  // ---- epilogue: lane owns node=col, 4 consecutive classes ----
  int node = brow + nrow;
  if (node < NN) {
#pragma unroll
    for (int m = 0; m < 5; ++m) {
      int c0 = m * 16 + (lane >> 4) * 4;
      f32x4 v = a2[m];
      if (c0 < NC) {
        uint2 pk;
        pk.x = ((unsigned)f2bf(v[1]) << 16) | f2bf(v[0]);
        pk.y = ((unsigned)f2bf(v[3]) << 16) | f2bf(v[2]);
        *(uint2*)(Pb + (size_t)node * 64 + c0) = pk;
      } else {
        if (c0 < 64) *(uint2*)(Pb + (size_t)node * 64 + c0) = make_uint2(0u, 0u);
        *(float4*)(R + (size_t)node * NC + (c0 - NC)) = make_float4(v[0], v[1], v[2], v[3]);
      }
    }
  }
}

// ---------------- final: out = log_softmax(mean-agg(p) + b2 + r), padded CSR ----------------
__global__ __launch_bounds__(256) void k_final(const unsigned short* __restrict__ Pb,
                                               const float* __restrict__ R,
                                               const int* __restrict__ row_ptr8,
                                               const int* __restrict__ deg,
                                               const int* __restrict__ csr8,
                                               const float* __restrict__ b2,
                                               float* __restrict__ out) {
  int w = threadIdx.x >> 6, lane = threadIdx.x & 63;
  int g = lane >> 4, r = lane & 15;
  int node = blockIdx.x * 4 + w;
  if (node >= NN) return;
  int dg = deg[node];
  int rs = row_ptr8[node];
  int nfull = ((dg + 7) & ~7) >> 3;
  float s0 = 0.f, s1 = 0.f, s2 = 0.f, s3 = 0.f;
  int e = rs + g;
  for (int it = 0; it < nfull; ++it, e += 8) {
    int sa = csr8[e];
    int sb = csr8[e + 4];
    uint2 va = *(const uint2*)(Pb + (size_t)sa * 64 + r * 4);
    uint2 vb = *(const uint2*)(Pb + (size_t)sb * 64 + r * 4);
    s0 += bflo(va.x) + bflo(vb.x);
    s1 += bfhi(va.x) + bfhi(vb.x);
    s2 += bflo(va.y) + bflo(vb.y);
    s3 += bfhi(va.y) + bfhi(vb.y);
  }
  s0 += __shfl_xor(s0, 16); s0 += __shfl_xor(s0, 32);
  s1 += __shfl_xor(s1, 16); s1 += __shfl_xor(s1, 32);
  s2 += __shfl_xor(s2, 16); s2 += __shfl_xor(s2, 32);
  s3 += __shfl_xor(s3, 16); s3 += __shfl_xor(s3, 32);

  float inv = 1.f / (float)(dg > 0 ? dg : 1);
  bool act = r < 10;
  float4 rr = act ? *(const float4*)(R + (size_t)node * NC + r * 4) : make_float4(0, 0, 0, 0);
  float4 bb = act ? *(const float4*)(b2 + r * 4) : make_float4(0, 0, 0, 0);
  float v0 = s0 * inv + rr.x + bb.x;
  float v1 = s1 * inv + rr.y + bb.y;
  float v2 = s2 * inv + rr.z + bb.z;
  float v3 = s3 * inv + rr.w + bb.w;
  float mx = act ? fmaxf(fmaxf(v0, v1), fmaxf(v2, v3)) : -1e30f;
#pragma unroll
  for (int o = 1; o < 16; o <<= 1) mx = fmaxf(mx, __shfl_xor(mx, o));
  float ex = act ? (__expf(v0 - mx) + __expf(v1 - mx) + __expf(v2 - mx) + __expf(v3 - mx)) : 0.f;
#pragma unroll
  for (int o = 1; o < 16; o <<= 1) ex += __shfl_xor(ex, o);
  float ls = mx + __logf(ex);
  if (g == 0 && act) {
    float4 o4 = make_float4(v0 - ls, v1 - ls, v2 - ls, v3 - ls);
    *(float4*)(out + (size_t)node * NC + r * 4) = o4;
  }
}

extern "C" void kernel_launch(void* const* d_in, const int* in_sizes, int n_in,
                              void* d_out, int out_size, void* d_ws, size_t ws_size,
                              hipStream_t stream) {
  const float* x   = (const float*)d_in[0];
  const int*   ei  = (const int*)d_in[1];
  const float* w1l = (const float*)d_in[2];
  const float* b1  = (const float*)d_in[3];
  const float* w1r = (const float*)d_in[4];
  const float* w2l = (const float*)d_in[5];
  const float* b2  = (const float*)d_in[6];
  const float* w2r = (const float*)d_in[7];
  float* out = (float*)d_out;
  const int* src = ei;
  const int* dst = ei + NE;

  char* ws = (char*)d_ws;
  size_t off = 0;
  auto alloc = [&](size_t bytes) -> char* {
    char* p = ws + off;
    off = (off + bytes + 255) & ~(size_t)255;
    return p;
  };
  int* bcnt     = (int*)alloc((size_t)(NBKT + 1) * 4);
  int* boff     = (int*)alloc((size_t)(NBKT + 1) * 4);
  int* bcur     = (int*)alloc((size_t)NBKT * 4);
  int* deg      = (int*)alloc((size_t)NN * 4);
  int* row_ptr8 = (int*)alloc((size_t)NN * 4);
  unsigned* pairs = (unsigned*)alloc((size_t)NE * 4);
  int* csr8     = (int*)alloc((size_t)(NE + BKT_SLACK * NBKT + 64) * 4);
  unsigned short* Wc  = (unsigned short*)alloc(256 * 256 * 2);
  unsigned short* W2c = (unsigned short*)alloc(80 * 256 * 2);
  unsigned*       xb  = (unsigned*)alloc((size_t)(NN + 1) * 64 * 4);
  unsigned*       A1  = (unsigned*)alloc((size_t)NN * 64 * 4);
  unsigned short* Pb  = (unsigned short*)alloc((size_t)(NN + 1) * 64 * 2);
  float*          R   = (float*)alloc((size_t)NN * NC * 4);

  hipMemsetAsync(bcnt, 0, (size_t)(NBKT + 1) * 4, stream);
  k_bhist<<<NBIN_BLOCKS, 256, 0, stream>>>(dst, bcnt);
  k_xbf16<<<((NN + 1) * 64 + 255) / 256, 256, 0, stream>>>(x, xb);
  k_bscan<<<1, 512, 0, stream>>>(bcnt, boff, bcur, Pb);
  k_bin<<<NBIN_BLOCKS, 256, 0, stream>>>(src, dst, bcur, pairs);
  k_csr<<<NBKT, 256, 0, stream>>>(pairs, boff, deg, row_ptr8, csr8);
  k_packw<<<336, 256, 0, stream>>>(w1l, w1r, w2l, w2r, Wc, W2c);
  k_agg1<<<(NN + 3) / 4, 256, 0, stream>>>(xb, row_ptr8, deg, csr8, A1);
  k_fused<<<(NN + 63) / 64, 256, 0, stream>>>((const unsigned short*)A1,
                                              (const unsigned short*)xb, Wc, b1, W2c, Pb, R);
  k_final<<<(NN + 3) / 4, 256, 0, stream>>>(Pb, R, row_ptr8, deg, csr8, b2, out);
}

// Round 12
// 308.194 us; speedup vs baseline: 1.0642x; 1.0642x over previous
//
#include <hip/hip_runtime.h>
#include <hip/hip_bf16.h>
#include <stdint.h>

#define NN 100000
#define NE 1600000
#define DF 128
#define DH 256
#define NC 40
#define BSHIFT 8
#define NBKT 391          // ceil(NN/256) buckets, bucket = dst>>8
#define EPB 8192          // edges per k_bin block
#define NBIN_BLOCKS ((NE + EPB - 1) / EPB)   // 196
#define BKT_SLACK 2048    // >= 7*256 max padding per bucket, 256-aligned

typedef __attribute__((ext_vector_type(8))) short short8;
typedef __attribute__((ext_vector_type(4))) float f32x4;

typedef const __attribute__((address_space(1))) unsigned int* gas1;
typedef __attribute__((address_space(3))) unsigned int* las3;

__device__ __forceinline__ void gload16(const void* g, void* l) {
  __builtin_amdgcn_global_load_lds((gas1)g, (las3)l, 16, 0, 0);
}

__device__ __forceinline__ unsigned short f2bf(float f) {
  union { float f; unsigned u; } v; v.f = f;
  unsigned r = v.u + 0x7FFFu + ((v.u >> 16) & 1u);
  return (unsigned short)(r >> 16);
}
__device__ __forceinline__ unsigned pack2(float a, float b) {
  return ((unsigned)f2bf(b) << 16) | f2bf(a);
}
__device__ __forceinline__ float bflo(unsigned u) {
  union { unsigned u; float f; } v; v.u = u << 16; return v.f;
}
__device__ __forceinline__ float bfhi(unsigned u) {
  union { unsigned u; float f; } v; v.u = u & 0xFFFF0000u; return v.f;
}

// ---------------- x -> bf16 pre-convert (+ zero row NN), 16B vectorized ----------------
__global__ void k_xbf16(const float* __restrict__ x, unsigned* __restrict__ xb) {
  int i = blockIdx.x * blockDim.x + threadIdx.x;   // quad of u32 (8 bf16)
  if (i < (NN + 1) * 16) {
    uint4 o = make_uint4(0u, 0u, 0u, 0u);
    if (i < NN * 16) {
      float4 a = ((const float4*)x)[2 * i];
      float4 b = ((const float4*)x)[2 * i + 1];
      o.x = pack2(a.x, a.y); o.y = pack2(a.z, a.w);
      o.z = pack2(b.x, b.y); o.w = pack2(b.z, b.w);
    }
    ((uint4*)xb)[i] = o;
  }
}

// ---------------- CSR build: bucket counting sort (padded output) ----------------
__global__ __launch_bounds__(512) void k_bhist(const int* __restrict__ dst, int* __restrict__ bcnt) {
  __shared__ int h[NBKT];
  int tid = threadIdx.x;
  for (int b = tid; b < NBKT; b += 512) h[b] = 0;
  __syncthreads();
  int base = blockIdx.x * EPB;
  int n = NE - base; if (n > EPB) n = EPB;
  for (int i = tid; i < n; i += 512) atomicAdd(&h[dst[base + i] >> BSHIFT], 1);
  __syncthreads();
  for (int b = tid; b < NBKT; b += 512) if (h[b]) atomicAdd(&bcnt[b], h[b]);
}

// scan buckets -> bases; init cursors; also zero Pb row NN
__global__ __launch_bounds__(512) void k_bscan(const int* __restrict__ bcnt,
                                               int* __restrict__ boff, int* __restrict__ bcur,
                                               unsigned short* __restrict__ Pb) {
  __shared__ int s[512];
  int tid = threadIdx.x;
  int v = (tid < NBKT) ? bcnt[tid] : 0;
  s[tid] = v;
  __syncthreads();
  for (int off = 1; off < 512; off <<= 1) {
    int a = (tid >= off) ? s[tid - off] : 0;
    __syncthreads();
    s[tid] += a;
    __syncthreads();
  }
  int excl = s[tid] - v;
  if (tid < NBKT) { boff[tid] = excl; bcur[tid] = excl; }
  if (tid == NBKT) boff[NBKT] = excl;   // == total (v=0 beyond NBKT)
  if (tid >= 448 && tid < 480) ((unsigned*)(Pb + (size_t)NN * 64))[tid - 448] = 0u;
}

__global__ __launch_bounds__(512) void k_bin(const int* __restrict__ src, const int* __restrict__ dst,
                                             int* __restrict__ bcur, unsigned* __restrict__ pairs) {
  __shared__ int hcnt[NBKT];
  __shared__ int hbase[NBKT];
  int tid = threadIdx.x;
  for (int b = tid; b < NBKT; b += 512) hcnt[b] = 0;
  __syncthreads();
  int base = blockIdx.x * EPB;
  int n = NE - base; if (n > EPB) n = EPB;
  for (int i = tid; i < n; i += 512) atomicAdd(&hcnt[dst[base + i] >> BSHIFT], 1);
  __syncthreads();
  for (int b = tid; b < NBKT; b += 512) hbase[b] = hcnt[b] ? atomicAdd(&bcur[b], hcnt[b]) : 0;
  __syncthreads();
  for (int b = tid; b < NBKT; b += 512) hcnt[b] = 0;
  __syncthreads();
  for (int i = tid; i < n; i += 512) {
    int s = src[base + i], d = dst[base + i];
    int b = d >> BSHIFT;
    int slot = atomicAdd(&hcnt[b], 1);
    pairs[hbase[b] + slot] = (unsigned)s | ((unsigned)(d & 255) << 17);
  }
}

// per-bucket padded CSR: deg[] + row_ptr8[] + csr8[] (lists padded to x8 with src=NN)
__global__ __launch_bounds__(1024) void k_csr(const unsigned* __restrict__ pairs,
                                              const int* __restrict__ boff,
                                              int* __restrict__ deg, int* __restrict__ row_ptr8,
                                              int* __restrict__ csr8) {
  __shared__ int ncnt[256];
  __shared__ int noff[256];
  int tid = threadIdx.x;
  int b = blockIdx.x;
  int base = boff[b], end = boff[b + 1];
  int base8 = base + BKT_SLACK * b;
  if (tid < 256) ncnt[tid] = 0;
  __syncthreads();
  for (int e = base + tid; e < end; e += 1024) atomicAdd(&ncnt[pairs[e] >> 17], 1);
  __syncthreads();
  int cnt = 0, pcnt = 0;
  if (tid < 256) { cnt = ncnt[tid]; pcnt = (cnt + 7) & ~7; noff[tid] = pcnt; }
  __syncthreads();
  for (int off = 1; off < 256; off <<= 1) {
    int a = 0;
    if (tid < 256 && tid >= off) a = noff[tid - off];
    __syncthreads();
    if (tid < 256) noff[tid] += a;
    __syncthreads();
  }
  int pexcl = 0;
  if (tid < 256) pexcl = noff[tid] - pcnt;
  __syncthreads();
  if (tid < 256) { noff[tid] = pexcl; ncnt[tid] = 0; }
  __syncthreads();
  if (tid < 256) {
    int gnode = (b << BSHIFT) + tid;
    if (gnode < NN) { deg[gnode] = cnt; row_ptr8[gnode] = base8 + pexcl; }
  }
  for (int e = base + tid; e < end; e += 1024) {
    unsigned p = pairs[e];
    int ld = p >> 17;
    int slot = atomicAdd(&ncnt[ld], 1);
    csr8[base8 + noff[ld] + slot] = (int)(p & 0x1FFFFu);
  }
  if (tid < 256) {
    for (int k = cnt; k < pcnt; ++k) csr8[base8 + pexcl + k] = NN;
  }
}

// ---------------- weight pack (f32 -> bf16, concat) ----------------
__global__ void k_packw(const float* __restrict__ w1l, const float* __restrict__ w1r,
                        const float* __restrict__ w2l, const float* __restrict__ w2r,
                        unsigned short* __restrict__ Wc, unsigned short* __restrict__ W2c) {
  int i = blockIdx.x * blockDim.x + threadIdx.x;
  if (i < 256 * 256) {
    int o = i >> 8, k = i & 255;
    float v = (k < 128) ? w1l[o * 128 + k] : w1r[o * 128 + (k - 128)];
    Wc[i] = f2bf(v);
  }
  int j = i - 256 * 256;
  if (j >= 0 && j < 80 * 256) {
    int o = j >> 8, k = j & 255;
    float v = (o < 40) ? w2l[o * 256 + k] : w2r[(o - 40) * 256 + k];
    W2c[j] = f2bf(v);
  }
}

// ---------------- layer-1 aggregation: A1 = mean-agg(xb), edge-paired dwordx2 gathers ----------------
// (measured at gather roofline: 410MB logical @ ~6.8 TB/s delivered, ~57% L2 hit; unchanged)
__global__ void k_agg1(const unsigned* __restrict__ xb, const int* __restrict__ row_ptr8,
                       const int* __restrict__ deg, const int* __restrict__ csr8,
                       unsigned* __restrict__ A1) {
  int w = threadIdx.x >> 6, lane = threadIdx.x & 63;
  int node = blockIdx.x * 4 + w;
  if (node >= NN) return;
  int dg = deg[node];
  int rs = row_ptr8[node];
  int pdeg = (dg + 7) & ~7;
  int half = lane >> 5, li = lane & 31;
  float a0 = 0.f, a1 = 0.f, a2 = 0.f, a3 = 0.f;
  const unsigned* xp = xb + li * 2;
  for (int e = rs; e < rs + pdeg; e += 8) {
#pragma unroll
    for (int j = 0; j < 4; ++j) {
      int idx = csr8[e + 2 * j + half];
      uint2 v = *(const uint2*)(xp + (size_t)idx * 64);
      a0 += bflo(v.x); a1 += bfhi(v.x);
      a2 += bflo(v.y); a3 += bfhi(v.y);
    }
  }
  a0 += __shfl_xor(a0, 32);
  a1 += __shfl_xor(a1, 32);
  a2 += __shfl_xor(a2, 32);
  a3 += __shfl_xor(a3, 32);
  if (half == 0) {
    float inv = 1.f / (float)(dg > 0 ? dg : 1);
    uint2 pk;
    pk.x = pack2(a0 * inv, a1 * inv);
    pk.y = pack2(a2 * inv, a3 * inv);
    *(uint2*)(A1 + (size_t)node * 64 + li * 2) = pk;
  }
}

// ---------------- fused GEMM1+GEMM2: H tile lives in LDS only ----------------
__global__ __launch_bounds__(256) void k_fused(const unsigned short* __restrict__ A1,
                                               const unsigned short* __restrict__ XB,
                                               const unsigned short* __restrict__ Wc,
                                               const float* __restrict__ b1,
                                               const unsigned short* __restrict__ W2c,
                                               unsigned short* __restrict__ Pb,
                                               float* __restrict__ R) {
  __shared__ __align__(16) unsigned short sA[64 * 64];
  __shared__ __align__(16) unsigned short sB[256 * 64];
  __shared__ __align__(16) unsigned short sH[64 * 256];
  int tid = threadIdx.x;
  int w = tid >> 6, lane = tid & 63;
  int brow = blockIdx.x * 64;
  int wr = (w >> 1) * 32, wc = (w & 1) * 128;
  f32x4 acc[2][8] = {};

  // ---- phase 1 ----
  for (int kt = 0; kt < 4; ++kt) {
    const unsigned short* srcA = (kt < 2) ? A1 : XB;
    int kcol = (kt & 1) * 64;
#pragma unroll
    for (int t = 0; t < 2; ++t) {
      int c = t * 256 + tid;
      int r = c >> 3, cc = c & 7;
      int scc = cc ^ (r & 7);
      int gr = brow + r; if (gr > NN - 1) gr = NN - 1;
      gload16(srcA + (size_t)gr * 128 + kcol + scc * 8, sA + c * 8);
    }
#pragma unroll
    for (int t = 0; t < 8; ++t) {
      int c = t * 256 + tid;
      int r = c >> 3, cc = c & 7;
      int scc = cc ^ (r & 7);
      gload16(Wc + (size_t)r * 256 + kt * 64 + scc * 8, sB + c * 8);
    }
    __syncthreads();
#pragma unroll
    for (int kg = 0; kg < 2; ++kg) {
      short8 af[2], bfr[8];
#pragma unroll
      for (int m = 0; m < 2; ++m) {
        int row = wr + m * 16 + (lane & 15);
        int cch = (kg * 4 + (lane >> 4)) ^ (row & 7);
        af[m] = *(const short8*)(sA + row * 64 + cch * 8);
      }
#pragma unroll
      for (int n = 0; n < 8; ++n) {
        int row = wc + n * 16 + (lane & 15);
        int cch = (kg * 4 + (lane >> 4)) ^ (row & 7);
        bfr[n] = *(const short8*)(sB + row * 64 + cch * 8);
      }
#pragma unroll
      for (int m = 0; m < 2; ++m)
#pragma unroll
        for (int n = 0; n < 8; ++n)
          acc[m][n] = __builtin_amdgcn_mfma_f32_16x16x32_bf16(af[m], bfr[n], acc[m][n], 0, 0, 0);
    }
    __syncthreads();
  }

  // ---- Htile -> sH (bias + relu, swizzled) ----
  {
    int colbase = wc + (lane & 15);
    int rowb = wr + (lane >> 4) * 4;
#pragma unroll
    for (int n = 0; n < 8; ++n) {
      int col = colbase + n * 16;
      float bias = b1[col];
      int g = col >> 3, off = col & 7;
#pragma unroll
      for (int m = 0; m < 2; ++m) {
        int row0 = rowb + m * 16;
#pragma unroll
        for (int q = 0; q < 4; ++q) {
          int row = row0 + q;
          float v = acc[m][n][q] + bias;
          v = v > 0.f ? v : 0.f;
          sH[row * 256 + ((g ^ (row & 7)) << 3) + off] = f2bf(v);
        }
      }
    }
  }
  __syncthreads();

  // ---- phase 2: P^T = W2c @ H^T ----
  f32x4 a2[5] = {};
  int nrow = w * 16 + (lane & 15);
  for (int kt = 0; kt < 4; ++kt) {
#pragma unroll
    for (int t = 0; t < 3; ++t) {
      int c = t * 256 + tid;
      if (c < 640) {
        int r = c >> 3, cc = c & 7;
        int scc = cc ^ (r & 7);
        gload16(W2c + (size_t)r * 256 + kt * 64 + scc * 8, sB + c * 8);
      }
    }
    __syncthreads();
#pragma unroll
    for (int kg = 0; kg < 2; ++kg) {
      int gH = kt * 8 + kg * 4 + (lane >> 4);
      short8 bf1 = *(const short8*)(sH + nrow * 256 + ((gH ^ (nrow & 7)) << 3));
      short8 af[5];
#pragma unroll
      for (int m = 0; m < 5; ++m) {
        int arow = m * 16 + (lane & 15);
        int cch = (kg * 4 + (lane >> 4)) ^ (arow & 7);
        af[m] = *(const short8*)(sB + arow * 64 + cch * 8);
      }
#pragma unroll
      for (int m = 0; m < 5; ++m)
        a2[m] = __builtin_amdgcn_mfma_f32_16x16x32_bf16(af[m], bf1, a2[m], 0, 0, 0);
    }
    __syncthreads();
  }

  // ---- epilogue: lane owns node=col, 4 consecutive classes ----
  int node = brow + nrow;
  if (node < NN) {
#pragma unroll
    for (int m = 0; m < 5; ++m) {
      int c0 = m * 16 + (lane >> 4) * 4;
      f32x4 v = a2[m];
      if (c0 < NC) {
        uint2 pk;
        pk.x = pack2(v[0], v[1]);
        pk.y = pack2(v[2], v[3]);
        *(uint2*)(Pb + (size_t)node * 64 + c0) = pk;
      } else {
        if (c0 < 64) *(uint2*)(Pb + (size_t)node * 64 + c0) = make_uint2(0u, 0u);
        *(float4*)(R + (size_t)node * NC + (c0 - NC)) = make_float4(v[0], v[1], v[2], v[3]);
      }
    }
  }
}

// ---------------- final: out = log_softmax(mean-agg(p) + b2 + r), padded CSR, 8 nodes/block ----------------
__global__ __launch_bounds__(512) void k_final(const unsigned short* __restrict__ Pb,
                                               const float* __restrict__ R,
                                               const int* __restrict__ row_ptr8,
                                               const int* __restrict__ deg,
                                               const int* __restrict__ csr8,
                                               const float* __restrict__ b2,
                                               float* __restrict__ out) {
  int w = threadIdx.x >> 6, lane = threadIdx.x & 63;
  int g = lane >> 4, r = lane & 15;
  int node = blockIdx.x * 8 + w;
  if (node >= NN) return;
  int dg = deg[node];
  int rs = row_ptr8[node];
  int nfull = ((dg + 7) & ~7) >> 3;
  float s0 = 0.f, s1 = 0.f, s2 = 0.f, s3 = 0.f;
  int e = rs + g;
  for (int it = 0; it < nfull; ++it, e += 8) {
    int sa = csr8[e];
    int sb = csr8[e + 4];
    uint2 va = *(const uint2*)(Pb + (size_t)sa * 64 + r * 4);
    uint2 vb = *(const uint2*)(Pb + (size_t)sb * 64 + r * 4);
    s0 += bflo(va.x) + bflo(vb.x);
    s1 += bfhi(va.x) + bfhi(vb.x);
    s2 += bflo(va.y) + bflo(vb.y);
    s3 += bfhi(va.y) + bfhi(vb.y);
  }
  s0 += __shfl_xor(s0, 16); s0 += __shfl_xor(s0, 32);
  s1 += __shfl_xor(s1, 16); s1 += __shfl_xor(s1, 32);
  s2 += __shfl_xor(s2, 16); s2 += __shfl_xor(s2, 32);
  s3 += __shfl_xor(s3, 16); s3 += __shfl_xor(s3, 32);

  float inv = 1.f / (float)(dg > 0 ? dg : 1);
  bool act = r < 10;
  float4 rr = act ? *(const float4*)(R + (size_t)node * NC + r * 4) : make_float4(0, 0, 0, 0);
  float4 bb = act ? *(const float4*)(b2 + r * 4) : make_float4(0, 0, 0, 0);
  float v0 = s0 * inv + rr.x + bb.x;
  float v1 = s1 * inv + rr.y + bb.y;
  float v2 = s2 * inv + rr.z + bb.z;
  float v3 = s3 * inv + rr.w + bb.w;
  float mx = act ? fmaxf(fmaxf(v0, v1), fmaxf(v2, v3)) : -1e30f;
#pragma unroll
  for (int o = 1; o < 16; o <<= 1) mx = fmaxf(mx, __shfl_xor(mx, o));
  float ex = act ? (__expf(v0 - mx) + __expf(v1 - mx) + __expf(v2 - mx) + __expf(v3 - mx)) : 0.f;
#pragma unroll
  for (int o = 1; o < 16; o <<= 1) ex += __shfl_xor(ex, o);
  float ls = mx + __logf(ex);
  if (g == 0 && act) {
    float4 o4 = make_float4(v0 - ls, v1 - ls, v2 - ls, v3 - ls);
    *(float4*)(out + (size_t)node * NC + r * 4) = o4;
  }
}

extern "C" void kernel_launch(void* const* d_in, const int* in_sizes, int n_in,
                              void* d_out, int out_size, void* d_ws, size_t ws_size,
                              hipStream_t stream) {
  const float* x   = (const float*)d_in[0];
  const int*   ei  = (const int*)d_in[1];
  const float* w1l = (const float*)d_in[2];
  const float* b1  = (const float*)d_in[3];
  const float* w1r = (const float*)d_in[4];
  const float* w2l = (const float*)d_in[5];
  const float* b2  = (const float*)d_in[6];
  const float* w2r = (const float*)d_in[7];
  float* out = (float*)d_out;
  const int* src = ei;
  const int* dst = ei + NE;

  char* ws = (char*)d_ws;
  size_t off = 0;
  auto alloc = [&](size_t bytes) -> char* {
    char* p = ws + off;
    off = (off + bytes + 255) & ~(size_t)255;
    return p;
  };
  int* bcnt     = (int*)alloc((size_t)(NBKT + 1) * 4);
  int* boff     = (int*)alloc((size_t)(NBKT + 1) * 4);
  int* bcur     = (int*)alloc((size_t)NBKT * 4);
  int* deg      = (int*)alloc((size_t)NN * 4);
  int* row_ptr8 = (int*)alloc((size_t)NN * 4);
  unsigned* pairs = (unsigned*)alloc((size_t)NE * 4);
  int* csr8     = (int*)alloc((size_t)(NE + BKT_SLACK * NBKT + 64) * 4);
  unsigned short* Wc  = (unsigned short*)alloc(256 * 256 * 2);
  unsigned short* W2c = (unsigned short*)alloc(80 * 256 * 2);
  unsigned*       xb  = (unsigned*)alloc((size_t)(NN + 1) * 64 * 4);
  unsigned*       A1  = (unsigned*)alloc((size_t)NN * 64 * 4);
  unsigned short* Pb  = (unsigned short*)alloc((size_t)(NN + 1) * 64 * 2);
  float*          R   = (float*)alloc((size_t)NN * NC * 4);

  hipMemsetAsync(bcnt, 0, (size_t)(NBKT + 1) * 4, stream);
  k_bhist<<<NBIN_BLOCKS, 512, 0, stream>>>(dst, bcnt);
  k_xbf16<<<((NN + 1) * 16 + 255) / 256, 256, 0, stream>>>(x, xb);
  k_bscan<<<1, 512, 0, stream>>>(bcnt, boff, bcur, Pb);
  k_bin<<<NBIN_BLOCKS, 512, 0, stream>>>(src, dst, bcur, pairs);
  k_csr<<<NBKT, 1024, 0, stream>>>(pairs, boff, deg, row_ptr8, csr8);
  k_packw<<<336, 256, 0, stream>>>(w1l, w1r, w2l, w2r, Wc, W2c);
  k_agg1<<<(NN + 3) / 4, 256, 0, stream>>>(xb, row_ptr8, deg, csr8, A1);
  k_fused<<<(NN + 63) / 64, 256, 0, stream>>>((const unsigned short*)A1,
                                              (const unsigned short*)xb, Wc, b1, W2c, Pb, R);
  k_final<<<(NN + 7) / 8, 512, 0, stream>>>(Pb, R, row_ptr8, deg, csr8, b2, out);
}